// Round 1
// baseline (874.303 us; speedup 1.0000x reference)
//
#include <hip/hip_runtime.h>
#include <hip/hip_bf16.h>
#include <stdint.h>

#define NNODES 10000
#define NEDGES 320000
#define DIM    256
#define KTOT   512
#define LN_EPS 1e-5f

typedef __attribute__((ext_vector_type(4))) float f32x4;
typedef __attribute__((ext_vector_type(8))) short bf16x8;

__device__ __forceinline__ ushort f2bf(float f) {
    union { float f; uint32_t u; } v; v.f = f;
    uint32_t r = v.u + 0x7fffu + ((v.u >> 16) & 1u);   // RNE
    return (ushort)(r >> 16);
}

// cast n4*4 floats -> bf16 (vectorized float4 -> ushort4)
__global__ void prep_cast(const float* __restrict__ src, ushort* __restrict__ dst, int n4) {
    int i = blockIdx.x * blockDim.x + threadIdx.x;
    if (i >= n4) return;
    float4 v = reinterpret_cast<const float4*>(src)[i];
    ushort4 o;
    o.x = f2bf(v.x); o.y = f2bf(v.y); o.z = f2bf(v.z); o.w = f2bf(v.w);
    reinterpret_cast<ushort4*>(dst)[i] = o;
}

// W [512][256] fp32 -> Wt [256][512] bf16, for both W_msg and W_upd
__global__ void prep_wt(const float* __restrict__ Wm, const float* __restrict__ Wu,
                        ushort* __restrict__ Wmt, ushort* __restrict__ Wut) {
    int tid = blockIdx.x * blockDim.x + threadIdx.x;   // 2*512*256 = 262144 threads
    int which = tid >> 17;
    int rem = tid & 131071;
    int k = rem >> 8, n = rem & 255;
    const float* s = which ? Wu : Wm;
    ushort*      d = which ? Wut : Wmt;
    d[n * KTOT + k] = f2bf(s[k * DIM + n]);
}

// Edge message GEMM + scatter-add.
// Block = 256 thr = 4 waves; block handles 64 edges; wave handles 16 edges x 256 cols.
// A = [x[row] ; x[col]] (bf16, gathered), B = W_msg^T bf16 [256][512].
__global__ __launch_bounds__(256)
void edge_gemm(const ushort* __restrict__ xb, const int* __restrict__ eidx,
               const ushort* __restrict__ Wmt, const float* __restrict__ bmsg,
               float* __restrict__ agg) {
    const int wave = threadIdx.x >> 6;
    const int lane = threadIdx.x & 63;
    const int ml = lane & 15;          // A-row / B-col / D-col lane index
    const int kg = lane >> 4;          // k-group (0..3)
    const int ebase = blockIdx.x * 64 + wave * 16;

    const int rowe = eidx[ebase + ml];
    const int cole = eidx[NEDGES + ebase + ml];
    const ushort* arow0 = xb + (size_t)rowe * DIM;  // k in [0,256)
    const ushort* arow1 = xb + (size_t)cole * DIM;  // k in [256,512)

    f32x4 acc[16];
#pragma unroll
    for (int nt = 0; nt < 16; ++nt) acc[nt] = (f32x4){0.f, 0.f, 0.f, 0.f};

#pragma unroll
    for (int kk = 0; kk < 16; ++kk) {
        const int k0 = kk * 32 + kg * 8;
        const ushort* ap = (kk < 8) ? (arow0 + k0) : (arow1 + (k0 - 256));
        bf16x8 a = *reinterpret_cast<const bf16x8*>(ap);
#pragma unroll
        for (int nt = 0; nt < 16; ++nt) {
            bf16x8 b = *reinterpret_cast<const bf16x8*>(Wmt + (size_t)(nt * 16 + ml) * KTOT + k0);
            acc[nt] = __builtin_amdgcn_mfma_f32_16x16x32_bf16(a, b, acc[nt], 0, 0, 0);
        }
    }

    // D layout: col = nt*16 + ml, row(edge) = kg*4 + i
    int dst[4];
#pragma unroll
    for (int i = 0; i < 4; ++i) dst[i] = eidx[NEDGES + ebase + kg * 4 + i];

#pragma unroll
    for (int nt = 0; nt < 16; ++nt) {
        const int c = nt * 16 + ml;
        const float bb = bmsg[c];
#pragma unroll
        for (int i = 0; i < 4; ++i) {
            float m = acc[nt][i] + bb;
            if (m > 0.f) atomicAdd(&agg[(size_t)dst[i] * DIM + c], m);  // relu: skip zeros
        }
    }
}

// Node update GEMM + bias + relu + LayerNorm. A = [x ; agg] bf16, B = W_upd^T.
__global__ __launch_bounds__(256)
void node_gemm_ln(const ushort* __restrict__ xb, const ushort* __restrict__ aggb,
                  const ushort* __restrict__ Wut, const float* __restrict__ bupd,
                  const float* __restrict__ gamma, const float* __restrict__ beta,
                  float* __restrict__ out) {
    const int wave = threadIdx.x >> 6;
    const int lane = threadIdx.x & 63;
    const int ml = lane & 15;
    const int kg = lane >> 4;
    const int nbase = blockIdx.x * 64 + wave * 16;

    const int nload = (nbase + ml < NNODES) ? (nbase + ml) : (NNODES - 1);
    const ushort* arow0 = xb   + (size_t)nload * DIM;
    const ushort* arow1 = aggb + (size_t)nload * DIM;

    f32x4 acc[16];
#pragma unroll
    for (int nt = 0; nt < 16; ++nt) acc[nt] = (f32x4){0.f, 0.f, 0.f, 0.f};

#pragma unroll
    for (int kk = 0; kk < 16; ++kk) {
        const int k0 = kk * 32 + kg * 8;
        const ushort* ap = (kk < 8) ? (arow0 + k0) : (arow1 + (k0 - 256));
        bf16x8 a = *reinterpret_cast<const bf16x8*>(ap);
#pragma unroll
        for (int nt = 0; nt < 16; ++nt) {
            bf16x8 b = *reinterpret_cast<const bf16x8*>(Wut + (size_t)(nt * 16 + ml) * KTOT + k0);
            acc[nt] = __builtin_amdgcn_mfma_f32_16x16x32_bf16(a, b, acc[nt], 0, 0, 0);
        }
    }

    // bias + relu; accumulate row sums for LN. Row r = kg*4+i lives in lanes sharing kg.
    float sum[4] = {0.f, 0.f, 0.f, 0.f}, ssq[4] = {0.f, 0.f, 0.f, 0.f};
#pragma unroll
    for (int nt = 0; nt < 16; ++nt) {
        const float bb = bupd[nt * 16 + ml];
#pragma unroll
        for (int i = 0; i < 4; ++i) {
            float v = acc[nt][i] + bb;
            v = v > 0.f ? v : 0.f;
            acc[nt][i] = v;
            sum[i] += v;
            ssq[i] += v * v;
        }
    }
#pragma unroll
    for (int m = 1; m < 16; m <<= 1) {
#pragma unroll
        for (int i = 0; i < 4; ++i) {
            sum[i] += __shfl_xor(sum[i], m);
            ssq[i] += __shfl_xor(ssq[i], m);
        }
    }
    float mu[4], rs[4];
#pragma unroll
    for (int i = 0; i < 4; ++i) {
        mu[i] = sum[i] * (1.f / 256.f);
        float var = ssq[i] * (1.f / 256.f) - mu[i] * mu[i];
        rs[i] = rsqrtf(var + LN_EPS);
    }
#pragma unroll
    for (int nt = 0; nt < 16; ++nt) {
        const int c = nt * 16 + ml;
        const float g = gamma[c], be = beta[c];
#pragma unroll
        for (int i = 0; i < 4; ++i) {
            const int node = nbase + kg * 4 + i;
            if (node < NNODES)
                out[(size_t)node * DIM + c] = (acc[nt][i] - mu[i]) * rs[i] * g + be;
        }
    }
}

extern "C" void kernel_launch(void* const* d_in, const int* in_sizes, int n_in,
                              void* d_out, int out_size, void* d_ws, size_t ws_size,
                              hipStream_t stream) {
    const float* x    = (const float*)d_in[0];
    const int*   eidx = (const int*)  d_in[1];
    const float* Wm   = (const float*)d_in[2];
    const float* bm   = (const float*)d_in[3];
    const float* Wu   = (const float*)d_in[4];
    const float* bu   = (const float*)d_in[5];
    const float* gam  = (const float*)d_in[6];
    const float* bet  = (const float*)d_in[7];
    float* out = (float*)d_out;

    char* ws = (char*)d_ws;
    float*  agg  = (float*) (ws);                    // 10,240,000 B
    ushort* xb   = (ushort*)(ws + 10240000);         //  5,120,000 B
    ushort* aggb = (ushort*)(ws + 15360000);         //  5,120,000 B
    ushort* Wmt  = (ushort*)(ws + 20480000);         //    262,144 B
    ushort* Wut  = (ushort*)(ws + 20742144);         //    262,144 B

    hipMemsetAsync(agg, 0, (size_t)NNODES * DIM * sizeof(float), stream);
    prep_cast<<<(NNODES * DIM / 4 + 255) / 256, 256, 0, stream>>>(x, xb, NNODES * DIM / 4);
    prep_wt<<<(2 * KTOT * DIM) / 256, 256, 0, stream>>>(Wm, Wu, Wmt, Wut);
    edge_gemm<<<NEDGES / 64, 256, 0, stream>>>(xb, eidx, Wmt, bm, agg);
    prep_cast<<<(NNODES * DIM / 4 + 255) / 256, 256, 0, stream>>>(agg, aggb, NNODES * DIM / 4);
    node_gemm_ln<<<(NNODES + 63) / 64, 256, 0, stream>>>(xb, aggb, Wut, bu, gam, bet, out);
}

// Round 2
// 524.230 us; speedup vs baseline: 1.6678x; 1.6678x over previous
//
#include <hip/hip_runtime.h>
#include <hip/hip_bf16.h>
#include <stdint.h>

#define NNODES 10000
#define NEDGES 320000
#define DIM    256
#define KTOT   512
#define LN_EPS 1e-5f
#define EPB    128   // edges per block in edge_gemm

typedef __attribute__((ext_vector_type(4))) float f32x4;
typedef __attribute__((ext_vector_type(8))) short bf16x8;

__device__ __forceinline__ ushort f2bf(float f) {
    union { float f; uint32_t u; } v; v.f = f;
    uint32_t r = v.u + 0x7fffu + ((v.u >> 16) & 1u);   // RNE
    return (ushort)(r >> 16);
}
__device__ __forceinline__ float bf2f(ushort u) {
    union { float f; uint32_t u; } v; v.u = ((uint32_t)u) << 16;
    return v.f;
}

// cast n4*4 floats -> bf16 (vectorized float4 -> ushort4)
__global__ void prep_cast(const float* __restrict__ src, ushort* __restrict__ dst, int n4) {
    int i = blockIdx.x * blockDim.x + threadIdx.x;
    if (i >= n4) return;
    float4 v = reinterpret_cast<const float4*>(src)[i];
    ushort4 o;
    o.x = f2bf(v.x); o.y = f2bf(v.y); o.z = f2bf(v.z); o.w = f2bf(v.w);
    reinterpret_cast<ushort4*>(dst)[i] = o;
}

// W [512][256] fp32 -> Wt [256][512] bf16, for both W_msg and W_upd
__global__ void prep_wt(const float* __restrict__ Wm, const float* __restrict__ Wu,
                        ushort* __restrict__ Wmt, ushort* __restrict__ Wut) {
    int tid = blockIdx.x * blockDim.x + threadIdx.x;   // 2*512*256 = 262144 threads
    int which = tid >> 17;
    int rem = tid & 131071;
    int k = rem >> 8, n = rem & 255;
    const float* s = which ? Wu : Wm;
    ushort*      d = which ? Wut : Wmt;
    d[n * KTOT + k] = f2bf(s[k * DIM + n]);
}

// ---- counting sort of edges by destination ----
__global__ void hist_k(const int* __restrict__ eidx, int* __restrict__ cnt) {
    int e = blockIdx.x * blockDim.x + threadIdx.x;
    if (e < NEDGES) atomicAdd(&cnt[eidx[NEDGES + e]], 1);
}

__global__ void scan_k(const int* __restrict__ cnt, int* __restrict__ cursor) {
    __shared__ int tsum[256];
    int t = threadIdx.x;
    int base = t * 40;                       // 256*40 = 10240 >= NNODES
    int s = 0;
    for (int i = 0; i < 40; ++i) { int idx = base + i; if (idx < NNODES) s += cnt[idx]; }
    tsum[t] = s;
    __syncthreads();
    if (t == 0) {
        int run = 0;
        for (int i = 0; i < 256; ++i) { int v = tsum[i]; tsum[i] = run; run += v; }
    }
    __syncthreads();
    int off = tsum[t];
    for (int i = 0; i < 40; ++i) {
        int idx = base + i;
        if (idx < NNODES) { cursor[idx] = off; off += cnt[idx]; }
    }
}

__global__ void scatter_k(const int* __restrict__ eidx, int* __restrict__ cursor,
                          int* __restrict__ srow, int* __restrict__ sdst) {
    int e = blockIdx.x * blockDim.x + threadIdx.x;
    if (e >= NEDGES) return;
    int d = eidx[NEDGES + e];
    int r = eidx[e];
    int p = atomicAdd(&cursor[d], 1);
    srow[p] = r;
    sdst[p] = d;
}

// ---- edge message GEMM over dst-sorted edges + in-LDS segmented reduce ----
// block = 256 thr = 4 waves; 128 edges/block; wave: 32 edges x 256 cols.
// B (W_msg^T) double-buffered in LDS per K=32 chunk, 80B-padded col stride.
__global__ __launch_bounds__(256)
void edge_gemm(const ushort* __restrict__ xb, const int* __restrict__ srow,
               const int* __restrict__ sdst, const ushort* __restrict__ Wmt,
               const float* __restrict__ bmsg, float* __restrict__ agg) {
    __shared__ ushort Bs[2][256 * 40];   // [buf][col*40 + k]  (40 ushorts = 80B padded stride)
    __shared__ ushort Ds[64][264];       // message staging window (bf16), padded
    __shared__ int dstS[64];

    const int tid  = threadIdx.x;
    const int wave = tid >> 6, lane = tid & 63;
    const int ml = lane & 15, kg = lane >> 4;
    const int ebase = blockIdx.x * EPB + wave * 32;

    // A row pointers: half 0 = x[src], half 1 = x[dst]  (concat along K)
    const ushort* aptr[2][2];
#pragma unroll
    for (int et = 0; et < 2; ++et) {
        int eg = ebase + et * 16 + ml;
        aptr[et][0] = xb + (size_t)srow[eg] * DIM;
        aptr[et][1] = xb + (size_t)sdst[eg] * DIM;
    }

    // B staging mapping: piece p = tid + 256j -> col = p>>2, seg = p&3 (16B each)
    const int scol = tid >> 2, sseg = tid & 3;
    int4 st[4];
    auto LOADW = [&](int kk) {
#pragma unroll
        for (int j = 0; j < 4; ++j)
            st[j] = *reinterpret_cast<const int4*>(Wmt + (size_t)(scol + 64 * j) * KTOT + kk * 32 + sseg * 8);
    };
    auto STOREW = [&](int b) {
#pragma unroll
        for (int j = 0; j < 4; ++j)
            *reinterpret_cast<int4*>(&Bs[b][(scol + 64 * j) * 40 + sseg * 8]) = st[j];
    };
    auto LOADA = [&](int kk, bf16x8* a) {
        const int k0 = kk * 32 + kg * 8;
        const int half = k0 >> 8;          // uniform in kk (kk<8 -> 0)
        const int off = k0 & 255;
        a[0] = *reinterpret_cast<const bf16x8*>(aptr[0][half] + off);
        a[1] = *reinterpret_cast<const bf16x8*>(aptr[1][half] + off);
    };

    f32x4 acc[2][16];
#pragma unroll
    for (int et = 0; et < 2; ++et)
#pragma unroll
        for (int nt = 0; nt < 16; ++nt) acc[et][nt] = (f32x4){0.f, 0.f, 0.f, 0.f};

    bf16x8 acur[2], anxt[2];
    LOADW(0);
    LOADA(0, acur);
    STOREW(0);
    __syncthreads();

    int cur = 0;
    for (int kk = 0; kk < 16; ++kk) {
        if (kk < 15) { LOADW(kk + 1); LOADA(kk + 1, anxt); }
#pragma unroll
        for (int nt = 0; nt < 16; ++nt) {
            bf16x8 b = *reinterpret_cast<const bf16x8*>(&Bs[cur][(nt * 16 + ml) * 40 + kg * 8]);
            acc[0][nt] = __builtin_amdgcn_mfma_f32_16x16x32_bf16(acur[0], b, acc[0][nt], 0, 0, 0);
            acc[1][nt] = __builtin_amdgcn_mfma_f32_16x16x32_bf16(acur[1], b, acc[1][nt], 0, 0, 0);
        }
        if (kk < 15) STOREW(cur ^ 1);
        __syncthreads();
        acur[0] = anxt[0]; acur[1] = anxt[1];
        cur ^= 1;
    }

    // Epilogue: bias+relu -> stage bf16 messages in 64-edge windows -> segmented
    // reduce (edges sorted by dst) -> few coalesced fp32 atomics per segment.
    const int mywin = wave >> 1;
    const int lbase = (wave & 1) * 32;
    for (int win = 0; win < 2; ++win) {
        if (mywin == win) {
#pragma unroll
            for (int nt = 0; nt < 16; ++nt) {
                float bb = bmsg[nt * 16 + ml];
#pragma unroll
                for (int et = 0; et < 2; ++et)
#pragma unroll
                    for (int i = 0; i < 4; ++i) {
                        float m = acc[et][nt][i] + bb;
                        m = m > 0.f ? m : 0.f;
                        Ds[lbase + et * 16 + kg * 4 + i][nt * 16 + ml] = f2bf(m);
                    }
            }
        }
        if (tid < 64) dstS[tid] = sdst[blockIdx.x * EPB + win * 64 + tid];
        __syncthreads();

        float s = 0.f;
        int dprev = dstS[0];
        for (int r = 0; r < 64; ++r) {
            int d = dstS[r];                       // uniform -> no divergence
            if (d != dprev) {
                if (s != 0.f) atomicAdd(&agg[(size_t)dprev * DIM + tid], s);
                s = 0.f; dprev = d;
            }
            s += bf2f(Ds[r][tid]);
        }
        if (s != 0.f) atomicAdd(&agg[(size_t)dprev * DIM + tid], s);
        __syncthreads();
    }
}

// Node update GEMM + bias + relu + LayerNorm. A = [x ; agg] bf16, B = W_upd^T.
__global__ __launch_bounds__(256)
void node_gemm_ln(const ushort* __restrict__ xb, const ushort* __restrict__ aggb,
                  const ushort* __restrict__ Wut, const float* __restrict__ bupd,
                  const float* __restrict__ gamma, const float* __restrict__ beta,
                  float* __restrict__ out) {
    const int wave = threadIdx.x >> 6;
    const int lane = threadIdx.x & 63;
    const int ml = lane & 15;
    const int kg = lane >> 4;
    const int nbase = blockIdx.x * 64 + wave * 16;

    const int nload = (nbase + ml < NNODES) ? (nbase + ml) : (NNODES - 1);
    const ushort* arow0 = xb   + (size_t)nload * DIM;
    const ushort* arow1 = aggb + (size_t)nload * DIM;

    f32x4 acc[16];
#pragma unroll
    for (int nt = 0; nt < 16; ++nt) acc[nt] = (f32x4){0.f, 0.f, 0.f, 0.f};

#pragma unroll
    for (int kk = 0; kk < 16; ++kk) {
        const int k0 = kk * 32 + kg * 8;
        const ushort* ap = (kk < 8) ? (arow0 + k0) : (arow1 + (k0 - 256));
        bf16x8 a = *reinterpret_cast<const bf16x8*>(ap);
#pragma unroll
        for (int nt = 0; nt < 16; ++nt) {
            bf16x8 b = *reinterpret_cast<const bf16x8*>(Wut + (size_t)(nt * 16 + ml) * KTOT + k0);
            acc[nt] = __builtin_amdgcn_mfma_f32_16x16x32_bf16(a, b, acc[nt], 0, 0, 0);
        }
    }

    float sum[4] = {0.f, 0.f, 0.f, 0.f}, ssq[4] = {0.f, 0.f, 0.f, 0.f};
#pragma unroll
    for (int nt = 0; nt < 16; ++nt) {
        const float bb = bupd[nt * 16 + ml];
#pragma unroll
        for (int i = 0; i < 4; ++i) {
            float v = acc[nt][i] + bb;
            v = v > 0.f ? v : 0.f;
            acc[nt][i] = v;
            sum[i] += v;
            ssq[i] += v * v;
        }
    }
#pragma unroll
    for (int m = 1; m < 16; m <<= 1) {
#pragma unroll
        for (int i = 0; i < 4; ++i) {
            sum[i] += __shfl_xor(sum[i], m);
            ssq[i] += __shfl_xor(ssq[i], m);
        }
    }
    float mu[4], rs[4];
#pragma unroll
    for (int i = 0; i < 4; ++i) {
        mu[i] = sum[i] * (1.f / 256.f);
        float var = ssq[i] * (1.f / 256.f) - mu[i] * mu[i];
        rs[i] = rsqrtf(var + LN_EPS);
    }
#pragma unroll
    for (int nt = 0; nt < 16; ++nt) {
        const int c = nt * 16 + ml;
        const float g = gamma[c], be = beta[c];
#pragma unroll
        for (int i = 0; i < 4; ++i) {
            const int node = nbase + kg * 4 + i;
            if (node < NNODES)
                out[(size_t)node * DIM + c] = (acc[nt][i] - mu[i]) * rs[i] * g + be;
        }
    }
}

extern "C" void kernel_launch(void* const* d_in, const int* in_sizes, int n_in,
                              void* d_out, int out_size, void* d_ws, size_t ws_size,
                              hipStream_t stream) {
    const float* x    = (const float*)d_in[0];
    const int*   eidx = (const int*)  d_in[1];
    const float* Wm   = (const float*)d_in[2];
    const float* bm   = (const float*)d_in[3];
    const float* Wu   = (const float*)d_in[4];
    const float* bu   = (const float*)d_in[5];
    const float* gam  = (const float*)d_in[6];
    const float* bet  = (const float*)d_in[7];
    float* out = (float*)d_out;

    char* ws = (char*)d_ws;
    float*  agg    = (float*) (ws);                    // 10,240,000 B
    ushort* xb     = (ushort*)(ws + 10240000);         //  5,120,000 B
    ushort* aggb   = (ushort*)(ws + 15360000);         //  5,120,000 B
    ushort* Wmt    = (ushort*)(ws + 20480000);         //    262,144 B
    ushort* Wut    = (ushort*)(ws + 20742144);         //    262,144 B
    int*    cnt    = (int*)   (ws + 21004288);         //     40,960 B
    int*    cursor = (int*)   (ws + 21045248);         //     40,960 B
    int*    srow   = (int*)   (ws + 21086208);         //  1,280,000 B
    int*    sdst   = (int*)   (ws + 22366208);         //  1,280,000 B  (end ~23.65 MB)

    hipMemsetAsync(agg, 0, (size_t)NNODES * DIM * sizeof(float), stream);
    hipMemsetAsync(cnt, 0, (size_t)NNODES * sizeof(int), stream);
    prep_cast<<<(NNODES * DIM / 4 + 255) / 256, 256, 0, stream>>>(x, xb, NNODES * DIM / 4);
    prep_wt<<<(2 * KTOT * DIM) / 256, 256, 0, stream>>>(Wm, Wu, Wmt, Wut);
    hist_k<<<(NEDGES + 255) / 256, 256, 0, stream>>>(eidx, cnt);
    scan_k<<<1, 256, 0, stream>>>(cnt, cursor);
    scatter_k<<<(NEDGES + 255) / 256, 256, 0, stream>>>(eidx, cursor, srow, sdst);
    edge_gemm<<<NEDGES / EPB, 256, 0, stream>>>(xb, srow, sdst, Wmt, bm, agg);
    prep_cast<<<(NNODES * DIM / 4 + 255) / 256, 256, 0, stream>>>(agg, aggb, NNODES * DIM / 4);
    node_gemm_ln<<<(NNODES + 63) / 64, 256, 0, stream>>>(xb, aggb, Wut, bu, gam, bet, out);
}

// Round 3
// 282.588 us; speedup vs baseline: 3.0939x; 1.8551x over previous
//
#include <hip/hip_runtime.h>
#include <hip/hip_bf16.h>
#include <stdint.h>

#define NNODES 10000
#define NEDGES 320000
#define DIM    256
#define KTOT   512
#define LN_EPS 1e-5f

typedef __attribute__((ext_vector_type(4))) float f32x4;
typedef __attribute__((ext_vector_type(8))) short bf16x8;

__device__ __forceinline__ ushort f2bf(float f) {
    union { float f; uint32_t u; } v; v.f = f;
    uint32_t r = v.u + 0x7fffu + ((v.u >> 16) & 1u);   // RNE
    return (ushort)(r >> 16);
}
__device__ __forceinline__ float bf2f(ushort u) {
    union { float f; uint32_t u; } v; v.u = ((uint32_t)u) << 16;
    return v.f;
}

// cast n4*4 floats -> bf16 (vectorized float4 -> ushort4)
__global__ void prep_cast(const float* __restrict__ src, ushort* __restrict__ dst, int n4) {
    int i = blockIdx.x * blockDim.x + threadIdx.x;
    if (i >= n4) return;
    float4 v = reinterpret_cast<const float4*>(src)[i];
    ushort4 o;
    o.x = f2bf(v.x); o.y = f2bf(v.y); o.z = f2bf(v.z); o.w = f2bf(v.w);
    reinterpret_cast<ushort4*>(dst)[i] = o;
}

// W_msg [512][256] fp32 -> Wa: fragment-arranged bf16 [half][kk][kg][col][8]
//   Wa[h*65536 + kk*4096 + kg*1024 + col*8 + j] = W_msg[kk*32+kg*8+j][h*128+col]
// W_upd [512][256] fp32 -> Wut [256][512] bf16 (plain transpose, node kernel)
__global__ void prep_wt(const float* __restrict__ Wm, const float* __restrict__ Wu,
                        ushort* __restrict__ Wa, ushort* __restrict__ Wut) {
    int tid = blockIdx.x * blockDim.x + threadIdx.x;   // 262144 threads
    if (tid < 131072) {
        int h   = tid >> 16;
        int rem = tid & 65535;
        int kk  = rem >> 12;
        int kg  = (rem >> 10) & 3;
        int col = (rem >> 3) & 127;
        int j   = rem & 7;
        int k = kk * 32 + kg * 8 + j;
        int n = (h << 7) + col;
        Wa[tid] = f2bf(Wm[k * DIM + n]);
    } else {
        int rem = tid - 131072;
        int n = rem >> 9, k = rem & 511;
        Wut[rem] = f2bf(Wu[k * DIM + n]);
    }
}

// ---- counting sort of edges by destination ----
__global__ void hist_k(const int* __restrict__ eidx, int* __restrict__ cnt) {
    int e = blockIdx.x * blockDim.x + threadIdx.x;
    if (e < NEDGES) atomicAdd(&cnt[eidx[NEDGES + e]], 1);
}

__global__ void scan_k(const int* __restrict__ cnt, int* __restrict__ cursor) {
    __shared__ int tsum[256];
    int t = threadIdx.x;
    int base = t * 40;
    int s = 0;
    for (int i = 0; i < 40; ++i) { int idx = base + i; if (idx < NNODES) s += cnt[idx]; }
    tsum[t] = s;
    __syncthreads();
    if (t == 0) {
        int run = 0;
        for (int i = 0; i < 256; ++i) { int v = tsum[i]; tsum[i] = run; run += v; }
    }
    __syncthreads();
    int off = tsum[t];
    for (int i = 0; i < 40; ++i) {
        int idx = base + i;
        if (idx < NNODES) { cursor[idx] = off; off += cnt[idx]; }
    }
}

__global__ void scatter_k(const int* __restrict__ eidx, int* __restrict__ cursor,
                          int* __restrict__ srow, int* __restrict__ sdst) {
    int e = blockIdx.x * blockDim.x + threadIdx.x;
    if (e >= NEDGES) return;
    int d = eidx[NEDGES + e];
    int r = eidx[e];
    int p = atomicAdd(&cursor[d], 1);
    srow[p] = r;
    sdst[p] = d;
}

// ---- edge message GEMM, barrier-free K-loop ----
// Grid: 625 edge-tiles x 2 col-halves. Block 512 thr = 8 waves, 512 edges/block.
// Wave: 64 edges x 128 cols; acc[et=4][nt=8] f32x4 = 128 VGPR.
// W half resident in LDS (128 KB, fragment-ordered); A gathered from global with
// 2-deep register prefetch; zero barriers inside the K-loop.
#define PREF(BUF, KN) do { \
    _Pragma("unroll") for (int et = 0; et < 4; ++et) { \
        const ushort* p = ((KN) < 8) ? (psrc[et] + (KN) * 32 + kg * 8) \
                                     : (pdst[et] + ((KN) - 8) * 32 + kg * 8); \
        BUF[et] = *reinterpret_cast<const bf16x8*>(p); } } while (0)

#define STEP(BUF, KK) do { \
    _Pragma("unroll") for (int nt = 0; nt < 8; ++nt) { \
        bf16x8 b = *reinterpret_cast<const bf16x8*>(&smem[(KK) * 4096 + kg * 1024 + (nt * 16 + ml) * 8]); \
        acc[0][nt] = __builtin_amdgcn_mfma_f32_16x16x32_bf16(BUF[0], b, acc[0][nt], 0, 0, 0); \
        acc[1][nt] = __builtin_amdgcn_mfma_f32_16x16x32_bf16(BUF[1], b, acc[1][nt], 0, 0, 0); \
        acc[2][nt] = __builtin_amdgcn_mfma_f32_16x16x32_bf16(BUF[2], b, acc[2][nt], 0, 0, 0); \
        acc[3][nt] = __builtin_amdgcn_mfma_f32_16x16x32_bf16(BUF[3], b, acc[3][nt], 0, 0, 0); } } while (0)

__global__ __launch_bounds__(512, 2)
void edge_gemm(const ushort* __restrict__ xb, const int* __restrict__ srow,
               const int* __restrict__ sdst, const ushort* __restrict__ Wa,
               const float* __restrict__ bmsg, float* __restrict__ agg) {
    __shared__ ushort smem[66048];   // Bs: 65536 (128KB W half) | Ds: 128 cols x 516 edges
    __shared__ int dstS[512];

    const int tid  = threadIdx.x;
    const int wave = tid >> 6, lane = tid & 63;
    const int ml = lane & 15, kg = lane >> 4;
    const int h     = blockIdx.x & 1;
    const int tile  = blockIdx.x >> 1;
    const int ebase = tile * 512;

    // per-lane edge row pointers (4 et groups of 16 edges)
    const ushort* psrc[4];
    const ushort* pdst[4];
#pragma unroll
    for (int et = 0; et < 4; ++et) {
        int e = ebase + wave * 64 + et * 16 + ml;
        psrc[et] = xb + (size_t)srow[e] * DIM;
        pdst[et] = xb + (size_t)sdst[e] * DIM;
    }
    dstS[tid] = sdst[ebase + tid];

    // early A prefetch (kk = 0,1) so gather latency overlaps W staging
    bf16x8 ab0[4], ab1[4], ab2[4];
    PREF(ab0, 0);
    PREF(ab1, 1);

    // stage W half into LDS: pure linear coalesced copy (Wa is pre-arranged)
    const ushort* wsrc = Wa + ((size_t)h << 16);
#pragma unroll
    for (int j = 0; j < 16; ++j) {
        int idx = j * 512 + tid;      // 16B chunk index, 0..8191
        *reinterpret_cast<int4*>(&smem[idx * 8]) =
            *reinterpret_cast<const int4*>(wsrc + idx * 8);
    }
    __syncthreads();

    f32x4 acc[4][8];
#pragma unroll
    for (int et = 0; et < 4; ++et)
#pragma unroll
        for (int nt = 0; nt < 8; ++nt) acc[et][nt] = (f32x4){0.f, 0.f, 0.f, 0.f};

#pragma unroll
    for (int kk = 0; kk < 16; ++kk) {
        if ((kk % 3) == 0)      { if (kk < 14) PREF(ab2, kk + 2); STEP(ab0, kk); }
        else if ((kk % 3) == 1) { if (kk < 14) PREF(ab0, kk + 2); STEP(ab1, kk); }
        else                    { if (kk < 14) PREF(ab1, kk + 2); STEP(ab2, kk); }
    }

    // ---- epilogue: bias+relu -> bf16 staging (reuse W LDS) -> segmented reduce ----
    __syncthreads();   // everyone done reading Bs
    const int hbase = h << 7;
#pragma unroll
    for (int nt = 0; nt < 8; ++nt) {
        const int c = nt * 16 + ml;
        const float bb = bmsg[hbase + c];
#pragma unroll
        for (int et = 0; et < 4; ++et) {
            ushort4 pk;
#pragma unroll
            for (int i = 0; i < 4; ++i) {
                float v = acc[et][nt][i] + bb;
                v = v > 0.f ? v : 0.f;
                ((ushort*)&pk)[i] = f2bf(v);
            }
            // Ds[col][edge]: stride 516 edges; lane's 4 rows are contiguous -> b64 write
            *reinterpret_cast<ushort4*>(&smem[c * 516 + wave * 64 + et * 16 + kg * 4]) = pk;
        }
    }
    __syncthreads();

    // segmented reduce: thread (c = tid&127, q = tid>>7) sums rows q*128..+127 of col c
    const int c = tid & 127, q = tid >> 7;
    const int rbase = q * 128;
    float s = 0.f;
    int dprev = dstS[rbase];
    for (int i = 0; i < 128; ++i) {
        int d = dstS[rbase + i];        // wave-uniform (q fixed per wave)
        if (d != dprev) {
            if (s != 0.f) atomicAdd(&agg[(size_t)dprev * DIM + hbase + c], s);
            s = 0.f; dprev = d;
        }
        s += bf2f(smem[c * 516 + rbase + i]);
    }
    if (s != 0.f) atomicAdd(&agg[(size_t)dprev * DIM + hbase + c], s);
}

#undef PREF
#undef STEP

// Node update GEMM + bias + relu + LayerNorm. A = [x ; agg] bf16, B = W_upd^T.
__global__ __launch_bounds__(256)
void node_gemm_ln(const ushort* __restrict__ xb, const ushort* __restrict__ aggb,
                  const ushort* __restrict__ Wut, const float* __restrict__ bupd,
                  const float* __restrict__ gamma, const float* __restrict__ beta,
                  float* __restrict__ out) {
    const int wave = threadIdx.x >> 6;
    const int lane = threadIdx.x & 63;
    const int ml = lane & 15;
    const int kg = lane >> 4;
    const int nbase = blockIdx.x * 64 + wave * 16;

    const int nload = (nbase + ml < NNODES) ? (nbase + ml) : (NNODES - 1);
    const ushort* arow0 = xb   + (size_t)nload * DIM;
    const ushort* arow1 = aggb + (size_t)nload * DIM;

    f32x4 acc[16];
#pragma unroll
    for (int nt = 0; nt < 16; ++nt) acc[nt] = (f32x4){0.f, 0.f, 0.f, 0.f};

#pragma unroll
    for (int kk = 0; kk < 16; ++kk) {
        const int k0 = kk * 32 + kg * 8;
        const ushort* ap = (kk < 8) ? (arow0 + k0) : (arow1 + (k0 - 256));
        bf16x8 a = *reinterpret_cast<const bf16x8*>(ap);
#pragma unroll
        for (int nt = 0; nt < 16; ++nt) {
            bf16x8 b = *reinterpret_cast<const bf16x8*>(Wut + (size_t)(nt * 16 + ml) * KTOT + k0);
            acc[nt] = __builtin_amdgcn_mfma_f32_16x16x32_bf16(a, b, acc[nt], 0, 0, 0);
        }
    }

    float sum[4] = {0.f, 0.f, 0.f, 0.f}, ssq[4] = {0.f, 0.f, 0.f, 0.f};
#pragma unroll
    for (int nt = 0; nt < 16; ++nt) {
        const float bb = bupd[nt * 16 + ml];
#pragma unroll
        for (int i = 0; i < 4; ++i) {
            float v = acc[nt][i] + bb;
            v = v > 0.f ? v : 0.f;
            acc[nt][i] = v;
            sum[i] += v;
            ssq[i] += v * v;
        }
    }
#pragma unroll
    for (int m = 1; m < 16; m <<= 1) {
#pragma unroll
        for (int i = 0; i < 4; ++i) {
            sum[i] += __shfl_xor(sum[i], m);
            ssq[i] += __shfl_xor(ssq[i], m);
        }
    }
    float mu[4], rs[4];
#pragma unroll
    for (int i = 0; i < 4; ++i) {
        mu[i] = sum[i] * (1.f / 256.f);
        float var = ssq[i] * (1.f / 256.f) - mu[i] * mu[i];
        rs[i] = rsqrtf(var + LN_EPS);
    }
#pragma unroll
    for (int nt = 0; nt < 16; ++nt) {
        const int c = nt * 16 + ml;
        const float g = gamma[c], be = beta[c];
#pragma unroll
        for (int i = 0; i < 4; ++i) {
            const int node = nbase + kg * 4 + i;
            if (node < NNODES)
                out[(size_t)node * DIM + c] = (acc[nt][i] - mu[i]) * rs[i] * g + be;
        }
    }
}

extern "C" void kernel_launch(void* const* d_in, const int* in_sizes, int n_in,
                              void* d_out, int out_size, void* d_ws, size_t ws_size,
                              hipStream_t stream) {
    const float* x    = (const float*)d_in[0];
    const int*   eidx = (const int*)  d_in[1];
    const float* Wm   = (const float*)d_in[2];
    const float* bm   = (const float*)d_in[3];
    const float* Wu   = (const float*)d_in[4];
    const float* bu   = (const float*)d_in[5];
    const float* gam  = (const float*)d_in[6];
    const float* bet  = (const float*)d_in[7];
    float* out = (float*)d_out;

    char* ws = (char*)d_ws;
    float*  agg    = (float*) (ws);                    // 10,240,000 B
    ushort* xb     = (ushort*)(ws + 10240000);         //  5,120,000 B
    ushort* aggb   = (ushort*)(ws + 15360000);         //  5,120,000 B
    ushort* Wa     = (ushort*)(ws + 20480000);         //    262,144 B (edge W, arranged)
    ushort* Wut    = (ushort*)(ws + 20742144);         //    262,144 B (node W^T)
    int*    cnt    = (int*)   (ws + 21004288);         //     40,960 B
    int*    cursor = (int*)   (ws + 21045248);         //     40,960 B
    int*    srow   = (int*)   (ws + 21086208);         //  1,280,000 B
    int*    sdst   = (int*)   (ws + 22366208);         //  1,280,000 B

    hipMemsetAsync(agg, 0, (size_t)NNODES * DIM * sizeof(float), stream);
    hipMemsetAsync(cnt, 0, (size_t)NNODES * sizeof(int), stream);
    prep_cast<<<(NNODES * DIM / 4 + 255) / 256, 256, 0, stream>>>(x, xb, NNODES * DIM / 4);
    prep_wt<<<(2 * KTOT * DIM) / 256, 256, 0, stream>>>(Wm, Wu, Wa, Wut);
    hist_k<<<(NEDGES + 255) / 256, 256, 0, stream>>>(eidx, cnt);
    scan_k<<<1, 256, 0, stream>>>(cnt, cursor);
    scatter_k<<<(NEDGES + 255) / 256, 256, 0, stream>>>(eidx, cursor, srow, sdst);
    edge_gemm<<<2 * (NEDGES / 512), 512, 0, stream>>>(xb, srow, sdst, Wa, bm, agg);
    prep_cast<<<(NNODES * DIM / 4 + 255) / 256, 256, 0, stream>>>(agg, aggb, NNODES * DIM / 4);
    node_gemm_ln<<<(NNODES + 63) / 64, 256, 0, stream>>>(xb, aggb, Wut, bu, gam, bet, out);
}